// Round 1
// 277.722 us; speedup vs baseline: 1.0867x; 1.0867x over previous
//
#include <hip/hip_runtime.h>
#include <math.h>

#define NB   128
#define CF   1024
#define RR   256
#define NA   312
#define DV   300
#define M2   320
#define MT   640
#define NKC  32

typedef _Float16 half8  __attribute__((ext_vector_type(8)));
typedef float float16v  __attribute__((ext_vector_type(16)));
typedef float float4v   __attribute__((ext_vector_type(4)));

// async global->LDS, 16B per lane. LDS dest must be wave-uniform base + lane*16,
// which holds for every use below (dest = smem_base + tid*16 + const).
__device__ __forceinline__ void gll16(const void* g, void* l) {
    __builtin_amdgcn_global_load_lds(
        (const __attribute__((address_space(1))) void*)g,
        (__attribute__((address_space(3))) void*)l, 16, 0, 0);
}

// ---- K1 fused: blocks 0..511 = prep (no-LDS transpose + sumsq partials),
//                blocks 512..1151 = Q projection (unchanged math) ----
__global__ void k_pq(const float* __restrict__ img, float* __restrict__ ssq4,
                     _Float16* __restrict__ avT,
                     const float* __restrict__ V, const float* __restrict__ W1,
                     const float* __restrict__ W2, _Float16* __restrict__ Qb) {
    int lin = blockIdx.x;
    if (lin < 512) {
        // prep: b = lin>>2, f-quarter q = lin&3 (8 kc-chunks of 32 f each)
        int q = lin & 3, b = lin >> 2;
        int t = threadIdx.x;
        int kk8 = t & 3;          // which 8-f group inside a 32-f chunk
        int rq  = t >> 2;         // r-quad: r = rq*4 .. rq*4+3
        float ss0 = 0.f, ss1 = 0.f, ss2 = 0.f, ss3 = 0.f;
        int kc0 = q * 8;
        for (int kc = kc0; kc < kc0 + 8; ++kc) {
            const float* src = img + ((size_t)b * CF + kc * 32 + kk8 * 8) * RR + rq * 4;
            float4v v[8];
            #pragma unroll
            for (int j = 0; j < 8; ++j) v[j] = *(const float4v*)(src + (size_t)j * RR);
            #pragma unroll
            for (int j = 0; j < 8; ++j) {
                ss0 += v[j][0] * v[j][0]; ss1 += v[j][1] * v[j][1];
                ss2 += v[j][2] * v[j][2]; ss3 += v[j][3] * v[j][3];
            }
            _Float16* dst = avT + ((size_t)(b * NKC + kc) * RR + rq * 4) * 32 + kk8 * 8;
            #pragma unroll
            for (int s = 0; s < 4; ++s) {
                half8 o;
                #pragma unroll
                for (int j = 0; j < 8; ++j) o[j] = (_Float16)v[j][s];
                *(half8*)(dst + (size_t)s * 32) = o;
            }
        }
        // reduce sumsq over the 4 kk8 lanes (adjacent lanes)
        ss0 += __shfl_xor(ss0, 1, 64); ss0 += __shfl_xor(ss0, 2, 64);
        ss1 += __shfl_xor(ss1, 1, 64); ss1 += __shfl_xor(ss1, 2, 64);
        ss2 += __shfl_xor(ss2, 1, 64); ss2 += __shfl_xor(ss2, 2, 64);
        ss3 += __shfl_xor(ss3, 1, 64); ss3 += __shfl_xor(ss3, 2, 64);
        if (kk8 == 0) {
            float4v sv; sv[0] = ss0; sv[1] = ss1; sv[2] = ss2; sv[3] = ss3;
            *(float4v*)(ssq4 + ((size_t)b * 4 + q) * RR + rq * 4) = sv;
        }
    } else {
        // Q projection (identical to previous k_q; grid flattened)
        int m   = lin - 512;
        int ib  = m % 160;
        int fch = m / 160;
        int t   = threadIdx.x;
        int f   = fch * 256 + t;
        bool isQ2 = ib >= 80;
        int i0l = (ib - (isQ2 ? 80 : 0)) * 4;
        int i0g = (isQ2 ? M2 : 0) + i0l;
        __shared__ float inv4[4];
        float acc[4] = {0, 0, 0, 0};
        bool zero = (i0l >= NA);
        if (!zero) {
            int row = t >> 6, l64 = t & 63;
            float s = 0.f;
            for (int v = l64; v < DV; v += 64) { float x = V[(i0l + row) * DV + v]; s += x * x; }
            #pragma unroll
            for (int o = 32; o; o >>= 1) s += __shfl_xor(s, o, 64);
            if (l64 == 0) inv4[row] = 1.f / fmaxf(sqrtf(s), 1e-12f);
            __syncthreads();
            const float* W = isQ2 ? W2 : W1;
            for (int v = 0; v < DV; v += 4) {
                float w0 = W[(size_t)(v + 0) * CF + f];
                float w1 = W[(size_t)(v + 1) * CF + f];
                float w2 = W[(size_t)(v + 2) * CF + f];
                float w3 = W[(size_t)(v + 3) * CF + f];
                #pragma unroll
                for (int ii = 0; ii < 4; ++ii) {
                    const float* Vr = V + (size_t)(i0l + ii) * DV + v;
                    acc[ii] += Vr[0] * w0 + Vr[1] * w1 + Vr[2] * w2 + Vr[3] * w3;
                }
            }
            #pragma unroll
            for (int ii = 0; ii < 4; ++ii) acc[ii] *= inv4[ii];
        }
        #pragma unroll
        for (int ii = 0; ii < 4; ++ii)
            Qb[((size_t)(f >> 5) * MT + (i0g + ii)) * 32 + (f & 31)] = (_Float16)acc[ii];
    }
}

// ---- K2: batched GEMM, M=128 x N=256, global_load_lds + counted vmcnt ----
__launch_bounds__(256, 2)
__global__ void k_gemm(const _Float16* __restrict__ Qb, const _Float16* __restrict__ avT,
                       const float* __restrict__ ssq4, float* __restrict__ out) {
    int lin  = blockIdx.x;
    int xcd  = lin & 7;
    int slot = lin >> 3;
    int bq   = slot / 5;
    int t2   = slot - bq * 5;
    int b    = bq * 8 + xcd;

    int tid = threadIdx.x;
    int lane = tid & 63, w = tid >> 6;
    int nl = lane & 31, kh = lane >> 5;

    __shared__ __align__(16) char smem[49152];
    _Float16* A0 = (_Float16*)smem;
    _Float16* A1 = (_Float16*)(smem + 8192);
    _Float16* B0 = (_Float16*)(smem + 16384);
    _Float16* B1 = (_Float16*)(smem + 32768);
    float* mred = (float*)smem;
    float* mg   = (float*)(smem + 1024);
    float* sred = (float*)(smem + 1280);
    float* dred = (float*)(smem + 2304);

    float16v acc[4][2];
    #pragma unroll
    for (int i = 0; i < 4; ++i)
        #pragma unroll
        for (int j = 0; j < 2; ++j)
            #pragma unroll
            for (int gi = 0; gi < 16; ++gi) acc[i][j][gi] = 0.f;

    int arow  = tid & 127;
    int akb0  = tid >> 7;
    int grow  = (arow < 64) ? (t2 * 64 + arow) : (M2 + t2 * 64 + (arow - 64));
    size_t a_src0 = (size_t)grow * 32 + akb0 * 8;
    const _Float16* bpanel = avT + (size_t)b * NKC * RR * 32;

    // 6 x 16B DMA per thread per stage: A tile 8KB + B tile 16KB, lane-linear dests
    #define STAGE(kc_, Ab, Bb) do {                                                  \
        const _Float16* as_ = Qb + (size_t)(kc_) * MT * 32 + a_src0;                 \
        gll16(as_,      (char*)(Ab) + tid * 16);                                     \
        gll16(as_ + 16, (char*)(Ab) + tid * 16 + 4096);                              \
        const _Float16* bs_ = bpanel + (size_t)(kc_) * RR * 32 + (size_t)tid * 32;   \
        gll16(bs_,      (char*)(Bb) + tid * 16);                                     \
        gll16(bs_ + 8,  (char*)(Bb) + tid * 16 + 4096);                              \
        gll16(bs_ + 16, (char*)(Bb) + tid * 16 + 8192);                              \
        gll16(bs_ + 24, (char*)(Bb) + tid * 16 + 12288);                             \
    } while (0)

    #define COMPUTE(Al, Bl) do {                                                     \
        _Pragma("unroll")                                                            \
        for (int ks = 0; ks < 2; ++ks) {                                             \
            int kb = ks * 2 + kh;                                                    \
            half8 b0f = *(const half8*)((Bl) + ((size_t)kb * 256 + w * 64 + nl) * 8);       \
            half8 b1f = *(const half8*)((Bl) + ((size_t)kb * 256 + w * 64 + 32 + nl) * 8);  \
            _Pragma("unroll")                                                        \
            for (int rf = 0; rf < 4; ++rf) {                                         \
                half8 af = *(const half8*)((Al) + ((size_t)kb * 128 + rf * 32 + nl) * 8);   \
                acc[rf][0] = __builtin_amdgcn_mfma_f32_32x32x16_f16(af, b0f, acc[rf][0], 0, 0, 0); \
                acc[rf][1] = __builtin_amdgcn_mfma_f32_32x32x16_f16(af, b1f, acc[rf][1], 0, 0, 0); \
            }                                                                        \
        }                                                                            \
    } while (0)

    STAGE(0, A0, B0);
    STAGE(1, A1, B1);
    asm volatile("s_waitcnt vmcnt(6)" ::: "memory");   // buf0 landed (mine)
    __builtin_amdgcn_s_barrier();                      // buf0 landed (all waves)
    __builtin_amdgcn_sched_barrier(0);

    #pragma unroll 1
    for (int kc = 0; kc < NKC - 2; kc += 2) {
        COMPUTE(A0, B0);                               // kc
        __builtin_amdgcn_s_barrier();                  // all done reading buf0
        __builtin_amdgcn_sched_barrier(0);
        STAGE(kc + 2, A0, B0);
        asm volatile("s_waitcnt vmcnt(6)" ::: "memory"); // kc+1 landed (mine)
        __builtin_amdgcn_s_barrier();                  // kc+1 landed (all)
        __builtin_amdgcn_sched_barrier(0);
        COMPUTE(A1, B1);                               // kc+1
        __builtin_amdgcn_s_barrier();                  // all done reading buf1
        __builtin_amdgcn_sched_barrier(0);
        STAGE(kc + 3, A1, B1);
        asm volatile("s_waitcnt vmcnt(6)" ::: "memory"); // kc+2 landed (mine)
        __builtin_amdgcn_s_barrier();                  // kc+2 landed (all)
        __builtin_amdgcn_sched_barrier(0);
    }
    COMPUTE(A0, B0);                                   // kc = 30
    asm volatile("s_waitcnt vmcnt(0)" ::: "memory");   // kc = 31 landed (mine)
    __builtin_amdgcn_s_barrier();                      // kc = 31 landed (all); also
    __builtin_amdgcn_sched_barrier(0);                 // fences epilogue smem reuse
    COMPUTE(A1, B1);                                   // kc = 31

    #undef STAGE
    #undef COMPUTE

    // inverse norms from the 4 per-quarter sumsq partials
    const float* sq = ssq4 + (size_t)b * 4 * RR;
    int c0 = w * 64 + nl;
    float p0 = sq[c0]      + sq[RR + c0]      + sq[2 * RR + c0]      + sq[3 * RR + c0];
    float p1 = sq[32 + c0] + sq[RR + 32 + c0] + sq[2 * RR + 32 + c0] + sq[3 * RR + 32 + c0];
    float iv0 = 1.f / fmaxf(sqrtf(p0), 1e-12f);
    float iv1 = 1.f / fmaxf(sqrtf(p1), 1e-12f);
    #pragma unroll
    for (int rf = 0; rf < 4; ++rf)
        #pragma unroll
        for (int gi = 0; gi < 16; ++gi) {
            acc[rf][0][gi] *= iv0;
            acc[rf][1][gi] *= iv1;
        }

    float mx[2][16];
    #pragma unroll
    for (int p = 0; p < 2; ++p)
        #pragma unroll
        for (int gi = 0; gi < 16; ++gi)
            mx[p][gi] = fmaxf(acc[p][0][gi], acc[p][1][gi]);
    #pragma unroll
    for (int off = 1; off <= 16; off <<= 1)
        #pragma unroll
        for (int p = 0; p < 2; ++p)
            #pragma unroll
            for (int gi = 0; gi < 16; ++gi)
                mx[p][gi] = fmaxf(mx[p][gi], __shfl_xor(mx[p][gi], off, 64));
    if (nl == 0) {
        #pragma unroll
        for (int p = 0; p < 2; ++p)
            #pragma unroll
            for (int gi = 0; gi < 16; ++gi) {
                int row = (gi & 3) + 8 * (gi >> 2) + 4 * kh;
                mred[(p * 32 + row) * 4 + w] = mx[p][gi];
            }
    }
    __syncthreads();
    if (tid < 64)
        mg[tid] = fmaxf(fmaxf(mred[tid * 4], mred[tid * 4 + 1]),
                        fmaxf(mred[tid * 4 + 2], mred[tid * 4 + 3]));
    __syncthreads();
    float sp[2][16], dp[2][16];
    #pragma unroll
    for (int p = 0; p < 2; ++p)
        #pragma unroll
        for (int gi = 0; gi < 16; ++gi) {
            int row = (gi & 3) + 8 * (gi >> 2) + 4 * kh;
            float m  = mg[p * 32 + row];
            float e0 = __expf(acc[p][0][gi] - m);
            float e1 = __expf(acc[p][1][gi] - m);
            sp[p][gi] = e0 + e1;
            dp[p][gi] = e0 * acc[p + 2][0][gi] + e1 * acc[p + 2][1][gi];
        }
    #pragma unroll
    for (int off = 1; off <= 16; off <<= 1)
        #pragma unroll
        for (int p = 0; p < 2; ++p)
            #pragma unroll
            for (int gi = 0; gi < 16; ++gi) {
                sp[p][gi] += __shfl_xor(sp[p][gi], off, 64);
                dp[p][gi] += __shfl_xor(dp[p][gi], off, 64);
            }
    if (nl == 0) {
        #pragma unroll
        for (int p = 0; p < 2; ++p)
            #pragma unroll
            for (int gi = 0; gi < 16; ++gi) {
                int row = (gi & 3) + 8 * (gi >> 2) + 4 * kh;
                sred[(p * 32 + row) * 4 + w] = sp[p][gi];
                dred[(p * 32 + row) * 4 + w] = dp[p][gi];
            }
    }
    __syncthreads();
    if (tid < 64) {
        float s = sred[tid * 4] + sred[tid * 4 + 1] + sred[tid * 4 + 2] + sred[tid * 4 + 3];
        float d = dred[tid * 4] + dred[tid * 4 + 1] + dred[tid * 4 + 2] + dred[tid * 4 + 3];
        int ig = t2 * 64 + tid;
        if (ig < NA) out[b * NA + ig] = d / s;
    }
}

// ---- launcher ----
extern "C" void kernel_launch(void* const* d_in, const int* in_sizes, int n_in,
                              void* d_out, int out_size, void* d_ws, size_t ws_size,
                              hipStream_t stream) {
    const float* img = (const float*)d_in[0];
    const float* V   = (const float*)d_in[1];
    const float* W1  = (const float*)d_in[2];
    const float* W2  = (const float*)d_in[3];
    float* out = (float*)d_out;

    char* ws = (char*)d_ws;
    size_t off = 0;
    float*    ssq4 = (float*)(ws + off);    off += (size_t)NB * 4 * RR * 4;
    _Float16* avT  = (_Float16*)(ws + off); off += (size_t)NB * CF * RR * 2;
    _Float16* Qb   = (_Float16*)(ws + off); off += (size_t)NKC * MT * 32 * 2;

    k_pq<<<dim3(1152), 256, 0, stream>>>(img, ssq4, avT, V, W1, W2, Qb);
    k_gemm<<<dim3(640), 256, 0, stream>>>(Qb, avT, ssq4, out);
}